// Round 6
// baseline (163.642 us; speedup 1.0000x reference)
//
#include <hip/hip_runtime.h>
#include <cstddef>
#include <cstdint>

#define NOBJ   16
#define FEAT   512
#define VIS    2048
#define NTGT   24
#define MROWS  4096
#define EROWS  32768

typedef __attribute__((ext_vector_type(8))) short short8;
typedef __attribute__((ext_vector_type(4))) float f32x4;
typedef __attribute__((ext_vector_type(16))) float f32x16;

__device__ __forceinline__ unsigned short f2bf(float f) {
    union { float f; unsigned int i; } v; v.f = f;
    const unsigned int x = v.i;
    return (unsigned short)((x + 0x7fffu + ((x >> 16) & 1u)) >> 16);  // RTNE
}

// async 16B global -> LDS (dest: wave-uniform base + lane*16)
__device__ __forceinline__ void gload16(const unsigned short* g, unsigned short* l) {
    __builtin_amdgcn_global_load_lds(
        (const __attribute__((address_space(1))) unsigned int*)(const void*)g,
        (__attribute__((address_space(3))) unsigned int*)(void*)l, 16, 0, 0);
}

// ---------------------------------------------------------------------------
// prep1: [0,1024) wtrans | [1024,1154) wchain1 | [1154,2178) src f32->bf16
//        | [2178,3202) zero P
__global__ __launch_bounds__(256)
void prep1(const float* __restrict__ w1, unsigned short* __restrict__ w1t,
           const float* __restrict__ wf, const float* __restrict__ bfv,
           const float* __restrict__ wr, float* __restrict__ t1,
           const float* __restrict__ src, unsigned short* __restrict__ srcb,
           float* __restrict__ P) {
    __shared__ float shbuf[FEAT * NTGT];   // 48 KB
    const int b   = blockIdx.x;
    const int tid = threadIdx.x;
    if (b < 1024) {
        float (*tile)[33] = (float(*)[33])shbuf;
        const int k0 = (b & 63) * 32;
        const int n0 = (b >> 6) * 32;
        const int tx = tid & 31, ty = tid >> 5;
        #pragma unroll
        for (int r = 0; r < 32; r += 8)
            tile[ty + r][tx] = w1[(size_t)(k0 + ty + r) * FEAT + n0 + tx];
        __syncthreads();
        #pragma unroll
        for (int r = 0; r < 32; r += 8)
            w1t[(size_t)(n0 + ty + r) * VIS + k0 + tx] = f2bf(tile[tx][ty + r]);
    } else if (b < 1154) {
        const int bb = b - 1024;           // 0..129
        const int h  = bb & 1;
        const float* wrh = wr + (size_t)h * FEAT * NTGT;
        for (int idx = tid; idx < FEAT * NTGT; idx += 256)
            shbuf[idx] = wrh[idx];
        __syncthreads();
        const int c    = tid & 31;
        const int krow = (bb >> 1) * 8 + (tid >> 5);   // 0..519
        if (krow > 512) return;
        const float* rowp = (krow < 512) ? (wf + (size_t)krow * FEAT) : bfv;
        const int ce = (c < NTGT) ? c : NTGT - 1;
        float s = 0.f;
        #pragma unroll 8
        for (int j = 0; j < FEAT; ++j)
            s = fmaf(rowp[j], shbuf[j * NTGT + ce], s);
        if (c < NTGT) t1[((size_t)h * 513 + krow) * 32 + c] = s;
    } else if (b < 2178) {
        const int bb = b - 1154;           // src convert: 1024 x 8192 elems
        #pragma unroll
        for (int q = 0; q < 4; ++q) {
            const size_t i = (size_t)bb * 8192 + q * 2048 + tid * 8;
            const float4 a = *reinterpret_cast<const float4*>(src + i);
            const float4 c = *reinterpret_cast<const float4*>(src + i + 4);
            short8 o;
            o[0] = (short)f2bf(a.x); o[1] = (short)f2bf(a.y);
            o[2] = (short)f2bf(a.z); o[3] = (short)f2bf(a.w);
            o[4] = (short)f2bf(c.x); o[5] = (short)f2bf(c.y);
            o[6] = (short)f2bf(c.z); o[7] = (short)f2bf(c.w);
            *reinterpret_cast<short8*>(srcb + i) = o;
        }
    } else {
        const int bb = b - 2178;
        P[(size_t)bb * 256 + tid] = 0.f;   // 4096*64 f32
    }
}

// ---------------------------------------------------------------------------
// prep2: wchain2 only (130 blocks)
__global__ __launch_bounds__(256)
void prep2(const float* __restrict__ w2, const float* __restrict__ b2,
           const float* __restrict__ t1, unsigned short* __restrict__ wABt,
           float* __restrict__ biasAB) {
    __shared__ float shbuf[FEAT * NTGT];   // 48 KB
    const int b   = blockIdx.x;
    const int tid = threadIdx.x;
    const int h   = b & 1;
    for (int idx = tid; idx < FEAT * NTGT; idx += 256) {
        const int row = idx / NTGT, col = idx - row * NTGT;
        shbuf[idx] = t1[((size_t)h * 513 + row) * 32 + col];
    }
    __syncthreads();
    const int c = tid & 31;
    const int r = (b >> 1) * 8 + (tid >> 5);
    if (r > 512) return;
    const float* rowp = (r < 512) ? (w2 + (size_t)r * FEAT) : b2;
    const int ce = (c < NTGT) ? c : NTGT - 1;
    float s = 0.f;
    #pragma unroll 8
    for (int k = 0; k < FEAT; ++k)
        s = fmaf(rowp[k], shbuf[k * NTGT + ce], s);
    if (c < NTGT) {
        const int q = h * NTGT + c;
        if (r < 512) wABt[(size_t)q * FEAT + r] = f2bf(s);
        else         biasAB[q] = s + t1[((size_t)h * 513 + 512) * 32 + c];
    }
}

// ---------------------------------------------------------------------------
// gemm1f v2: BM=128 BN=32 BK=64, 4 waves each one 32x32 tile via
// mfma_f32_32x32x16_bf16 (acc f32x16). A(16KB)+B(4KB) staged per iter with
// global_load_lds (linear LDS, inverse-swizzled global source), dbuf.
// Epilogue: bias+relu+pack -> Ht[128][40], fused projection into P (atomic).
__global__ __launch_bounds__(256)
void gemm1f(const unsigned short* __restrict__ srcb, const unsigned short* __restrict__ w1t,
            const float* __restrict__ b1, const unsigned short* __restrict__ wABt,
            float* __restrict__ P) {
    __shared__ __align__(16) unsigned short As[2][128 * 64];  // 32 KB
    __shared__ __align__(16) unsigned short Bs[2][32 * 64];   //  8 KB

    // XCD-aware: 4 m-panels x 16 n-panels per XCD (A 2MB + w1t 2MB = L2-fit).
    const int bid = blockIdx.x;
    const int xcd = bid & 7;
    const int k8  = bid >> 3;               // 0..63
    const int xb  = k8 & 15;                // n-panel 0..15
    const int yb  = (xcd << 2) | (k8 >> 4); // m-panel 0..31
    const int m0 = yb * 128;
    const int n0 = xb * 32;

    const int tid  = threadIdx.x;
    const int lane = tid & 63;
    const int wid  = tid >> 6;              // wave owns rows [wid*32, +32)

    // staging maps (inverse-swizzled global source, linear LDS dest)
    const int aRow = tid >> 3, aCd = (tid & 7) ^ (aRow & 7);
    const int bN   = tid >> 3, bCd = (tid & 7) ^ (bN & 7);
    const size_t aOff = (size_t)(m0 + aRow) * VIS + (aCd << 3);
    const size_t bOff = (size_t)(n0 + bN) * VIS + (bCd << 3);
    const int ldsWb = (wid * 64) << 3;      // wave-uniform slot base (ushorts)

    f32x16 acc = {};

    // prologue: stage tile 0
    #pragma unroll
    for (int q = 0; q < 4; ++q)
        gload16(srcb + aOff + (size_t)q * 32 * VIS, &As[0][(q * 256) * 8 + ldsWb]);
    gload16(w1t + bOff, &Bs[0][ldsWb]);
    __syncthreads();

    int cur = 0;
    for (int t = 0; t < VIS / 64; ++t) {
        if (t + 1 < VIS / 64) {             // issue next-tile loads first
            const int kn = (t + 1) * 64;
            #pragma unroll
            for (int q = 0; q < 4; ++q)
                gload16(srcb + aOff + (size_t)q * 32 * VIS + kn,
                        &As[cur ^ 1][(q * 256) * 8 + ldsWb]);
            gload16(w1t + bOff + kn, &Bs[cur ^ 1][ldsWb]);
        }
        #pragma unroll
        for (int k2 = 0; k2 < 4; ++k2) {    // K=64 in 4 x K16 steps
            const int chunk = (k2 << 1) + (lane >> 5);
            short8 af, bf8;
            {
                const int row = wid * 32 + (lane & 31);
                const int cw  = chunk ^ (row & 7);
                af = *reinterpret_cast<const short8*>(&As[cur][(row << 6) + (cw << 3)]);
            }
            {
                const int n  = lane & 31;
                const int cw = chunk ^ (n & 7);
                bf8 = *reinterpret_cast<const short8*>(&Bs[cur][(n << 6) + (cw << 3)]);
            }
            acc = __builtin_amdgcn_mfma_f32_32x32x16_bf16(af, bf8, acc, 0, 0, 0);
        }
        __syncthreads();
        cur ^= 1;
    }

    // ---------------- epilogue: bias+relu+pack -> Ht[128][40] ----------------
    unsigned short* Ht = &As[0][0];
    {
        const float bias = b1[n0 + (lane & 31)];
        #pragma unroll
        for (int r = 0; r < 16; ++r) {
            const int row = wid * 32 + (r & 3) + ((r >> 2) << 3) + ((lane >> 5) << 2);
            const float v = fmaxf(acc[r] + bias, 0.f);
            Ht[row * 40 + (lane & 31)] = f2bf(v);
        }
    }
    __syncthreads();

    // fused projection: wave handles rows [wid*32,+32): 2 m-frags x 3 q-frags
    short8 bq[3];
    #pragma unroll
    for (int t3 = 0; t3 < 3; ++t3)
        bq[t3] = *reinterpret_cast<const short8*>(
            wABt + (size_t)(t3 * 16 + (lane & 15)) * FEAT + n0 + ((lane >> 4) << 3));

    const f32x4 pz = {0.f, 0.f, 0.f, 0.f};
    #pragma unroll
    for (int fr = 0; fr < 2; ++fr) {
        short8 aep;
        {
            const int m = wid * 32 + fr * 16 + (lane & 15);
            aep = *reinterpret_cast<const short8*>(&Ht[m * 40 + ((lane >> 4) << 3)]);
        }
        #pragma unroll
        for (int t3 = 0; t3 < 3; ++t3) {
            f32x4 pp = __builtin_amdgcn_mfma_f32_16x16x32_bf16(aep, bq[t3], pz, 0, 0, 0);
            const int q  = t3 * 16 + (lane & 15);
            const int mb = m0 + wid * 32 + fr * 16 + ((lane >> 4) << 2);
            #pragma unroll
            for (int r = 0; r < 4; ++r)
                atomicAdd(&P[(size_t)(mb + r) * 64 + q], pp[r]);
        }
    }
}

// ---------------------------------------------------------------------------
__global__ __launch_bounds__(256)
void out_loss_kernel(const float* __restrict__ P, const float* __restrict__ br,
                     const float* __restrict__ biasAB, const int* __restrict__ tgt,
                     float* __restrict__ out, float* __restrict__ out_tgt,
                     float* __restrict__ partials) {
    __shared__ float sm[32][49];
    const int bt  = blockIdx.x;
    const int tid = threadIdx.x;
    for (int idx = tid; idx < 32 * 48; idx += 256) {
        const int row = idx / 48, col = idx - row * 48;
        sm[row][col] = P[(size_t)(bt * 32 + row) * 64 + col];
    }
    __syncthreads();

    const int r  = bt * 256 + tid;
    const int i  = tid >> 4, j = tid & 15;
    const int tg = tgt[r];

    float vals[NTGT];
    float mx = -1e30f, vtg = 0.f;
    #pragma unroll
    for (int t = 0; t < NTGT; ++t) {
        const float cv = br[t] + biasAB[t] + biasAB[24 + t];
        const float v  = sm[i][t] + sm[16 + j][24 + t] + cv;
        vals[t] = v;
        mx = fmaxf(mx, v);
        if (t == tg) vtg = v;
    }
    float se = 0.f;
    #pragma unroll
    for (int t = 0; t < NTGT; ++t) se += expf(vals[t] - mx);
    const float lse = mx + logf(se);

    float4* o4 = reinterpret_cast<float4*>(out + (size_t)r * NTGT);
    #pragma unroll
    for (int q = 0; q < 6; ++q)
        o4[q] = make_float4(vals[q * 4], vals[q * 4 + 1], vals[q * 4 + 2], vals[q * 4 + 3]);
    out_tgt[r] = (float)tg;

    const float wcl = (tg == 0) ? 1.f : 100.f;
    float p1 = wcl * (lse - vtg);
    float p2 = wcl;
    #pragma unroll
    for (int off = 32; off > 0; off >>= 1) {
        p1 += __shfl_down(p1, off);
        p2 += __shfl_down(p2, off);
    }
    __shared__ float s1[4], s2[4];
    const int lane = tid & 63, wv = tid >> 6;
    if (lane == 0) { s1[wv] = p1; s2[wv] = p2; }
    __syncthreads();
    if (tid == 0) {
        partials[bt]       = s1[0] + s1[1] + s1[2] + s1[3];
        partials[128 + bt] = s2[0] + s2[1] + s2[2] + s2[3];
    }
}

__global__ void final_loss(const float* __restrict__ partials, float* __restrict__ loss) {
    const int t = threadIdx.x;                       // 64 threads
    float a = partials[t] + partials[t + 64];
    float b = partials[128 + t] + partials[192 + t];
    #pragma unroll
    for (int off = 32; off > 0; off >>= 1) {
        a += __shfl_down(a, off);
        b += __shfl_down(b, off);
    }
    if (t == 0) loss[0] = a / b;
}

// ---------------------------------------------------------------------------
extern "C" void kernel_launch(void* const* d_in, const int* in_sizes, int n_in,
                              void* d_out, int out_size, void* d_ws, size_t ws_size,
                              hipStream_t stream) {
    const float* src = (const float*)d_in[0];
    const int*   tgt = (const int*)d_in[1];
    const float* w1  = (const float*)d_in[2];
    const float* b1  = (const float*)d_in[3];
    const float* w2  = (const float*)d_in[4];
    const float* b2  = (const float*)d_in[5];
    const float* wf  = (const float*)d_in[6];
    const float* bfv = (const float*)d_in[7];
    const float* wr  = (const float*)d_in[8];
    const float* br  = (const float*)d_in[9];

    float* ws = (float*)d_ws;
    unsigned short* w1t   = (unsigned short*)(ws);             // 512x2048 bf16
    unsigned short* srcb  = (unsigned short*)(ws + 524288);    // 4096x2048 bf16
    float*          t1    = ws + 4718592;                      // 2*513*32 f32
    unsigned short* wABt  = (unsigned short*)(ws + 4751424);   // 48x512 bf16
    float*          biasAB = ws + 4763712;                     // 48 (+pad)
    float*          P     = ws + 4763776;                      // 4096x64 f32
    float*          parts = ws + 5025920;                      // 256 f32

    float* out_logits = (float*)d_out;
    float* out_tgt    = out_logits + (size_t)EROWS * NTGT;
    float* out_lossp  = out_tgt + EROWS;

    prep1<<<3202, 256, 0, stream>>>(w1, w1t, wf, bfv, wr, t1, src, srcb, P);
    prep2<<<130, 256, 0, stream>>>(w2, b2, t1, wABt, biasAB);
    gemm1f<<<512, 256, 0, stream>>>(srcb, w1t, b1, wABt, P);
    out_loss_kernel<<<128, 256, 0, stream>>>(P, br, biasAB, tgt,
                                             out_logits, out_tgt, parts);
    final_loss<<<1, 64, 0, stream>>>(parts, out_lossp);
}

// Round 8
// 160.205 us; speedup vs baseline: 1.0215x; 1.0215x over previous
//
#include <hip/hip_runtime.h>
#include <cstddef>
#include <cstdint>

#define NOBJ   16
#define FEAT   512
#define VIS    2048
#define NTGT   24
#define MROWS  4096
#define EROWS  32768

typedef __attribute__((ext_vector_type(8))) short short8;
typedef __attribute__((ext_vector_type(4))) float f32x4;
typedef __attribute__((ext_vector_type(16))) float f32x16;

__device__ __forceinline__ unsigned short f2bf(float f) {
    union { float f; unsigned int i; } v; v.f = f;
    const unsigned int x = v.i;
    return (unsigned short)((x + 0x7fffu + ((x >> 16) & 1u)) >> 16);  // RTNE
}

// async 16B global -> LDS (dest: wave-uniform base + lane*16)
__device__ __forceinline__ void gload16(const unsigned short* g, unsigned short* l) {
    __builtin_amdgcn_global_load_lds(
        (const __attribute__((address_space(1))) unsigned int*)(const void*)g,
        (__attribute__((address_space(3))) unsigned int*)(void*)l, 16, 0, 0);
}

// ---------------------------------------------------------------------------
// prep1: [0,1024) wtrans | [1024,1050) wchain1 | [1050,2074) src f32->bf16
//        | [2074,3098) zero P
__global__ __launch_bounds__(256)
void prep1(const float* __restrict__ w1, unsigned short* __restrict__ w1t,
           const float* __restrict__ wf, const float* __restrict__ bfv,
           const float* __restrict__ wr, float* __restrict__ t1,
           const float* __restrict__ src, unsigned short* __restrict__ srcb,
           float* __restrict__ P) {
    __shared__ float shbuf[FEAT * NTGT];   // 48 KB
    const int b   = blockIdx.x;
    const int tid = threadIdx.x;
    if (b < 1024) {
        float (*tile)[33] = (float(*)[33])shbuf;
        const int k0 = (b & 63) * 32;
        const int n0 = (b >> 6) * 32;
        const int tx = tid & 31, ty = tid >> 5;
        #pragma unroll
        for (int r = 0; r < 32; r += 8)
            tile[ty + r][tx] = w1[(size_t)(k0 + ty + r) * FEAT + n0 + tx];
        __syncthreads();
        #pragma unroll
        for (int r = 0; r < 32; r += 8)
            w1t[(size_t)(n0 + ty + r) * VIS + k0 + tx] = f2bf(tile[tx][ty + r]);
    } else if (b < 1050) {
        // wchain1, c-grouped float4: t1[h][krow][c] = sum_j rowk[j]*wr[h][j][c]
        const int bb = b - 1024;           // 0..25
        const int h  = bb / 13, blk = bb % 13;
        const float* wrh = wr + (size_t)h * FEAT * NTGT;
        for (int idx = tid; idx < FEAT * NTGT; idx += 256)
            shbuf[idx] = wrh[idx];
        __syncthreads();
        if (tid < 252) {
            const int krow = blk * 42 + tid / 6;
            const int cg   = tid % 6;
            if (krow <= 512) {
                const float* rowp = (krow < 512) ? (wf + (size_t)krow * FEAT) : bfv;
                const f32x4* shb4 = (const f32x4*)shbuf;
                f32x4 p = {0.f, 0.f, 0.f, 0.f};
                #pragma unroll 4
                for (int j = 0; j < FEAT; j += 4) {
                    const float4 a = *reinterpret_cast<const float4*>(rowp + j);
                    const f32x4 w0 = shb4[(j + 0) * 6 + cg];
                    const f32x4 w1v = shb4[(j + 1) * 6 + cg];
                    const f32x4 w2v = shb4[(j + 2) * 6 + cg];
                    const f32x4 w3v = shb4[(j + 3) * 6 + cg];
                    p += a.x * w0 + a.y * w1v + a.z * w2v + a.w * w3v;
                }
                *reinterpret_cast<f32x4*>(t1 + ((size_t)h * 513 + krow) * 32 + cg * 4) = p;
            }
        }
    } else if (b < 2074) {
        const int bb = b - 1050;           // src convert: 1024 x 8192 elems
        #pragma unroll
        for (int q = 0; q < 4; ++q) {
            const size_t i = (size_t)bb * 8192 + q * 2048 + tid * 8;
            const float4 a = *reinterpret_cast<const float4*>(src + i);
            const float4 c = *reinterpret_cast<const float4*>(src + i + 4);
            short8 o;
            o[0] = (short)f2bf(a.x); o[1] = (short)f2bf(a.y);
            o[2] = (short)f2bf(a.z); o[3] = (short)f2bf(a.w);
            o[4] = (short)f2bf(c.x); o[5] = (short)f2bf(c.y);
            o[6] = (short)f2bf(c.z); o[7] = (short)f2bf(c.w);
            *reinterpret_cast<short8*>(srcb + i) = o;
        }
    } else {
        const int bb = b - 2074;
        P[(size_t)bb * 256 + tid] = 0.f;   // 4096*64 f32
    }
}

// ---------------------------------------------------------------------------
// prep2: wchain2, c-grouped float4 (26 blocks).
// wABt[q=h*24+c][r] = bf16(sum_k w2[r][k]*t1[h][k][c]); r==512 -> biasAB
__global__ __launch_bounds__(256)
void prep2(const float* __restrict__ w2, const float* __restrict__ b2,
           const float* __restrict__ t1, unsigned short* __restrict__ wABt,
           float* __restrict__ biasAB) {
    __shared__ float shbuf[FEAT * NTGT];   // 48 KB, packed [k][c] 24 cols
    const int b   = blockIdx.x;            // 0..25
    const int tid = threadIdx.x;
    const int h   = b / 13, blk = b % 13;
    for (int idx = tid; idx < FEAT * NTGT; idx += 256) {
        const int row = idx / NTGT, col = idx - row * NTGT;
        shbuf[idx] = t1[((size_t)h * 513 + row) * 32 + col];
    }
    __syncthreads();
    if (tid >= 252) return;
    const int r  = blk * 42 + tid / 6;
    const int cg = tid % 6;
    if (r > 512) return;
    const float* rowp = (r < 512) ? (w2 + (size_t)r * FEAT) : b2;
    const f32x4* shb4 = (const f32x4*)shbuf;
    f32x4 p = {0.f, 0.f, 0.f, 0.f};
    #pragma unroll 4
    for (int k = 0; k < FEAT; k += 4) {
        const float4 a = *reinterpret_cast<const float4*>(rowp + k);
        const f32x4 w0 = shb4[(k + 0) * 6 + cg];
        const f32x4 w1v = shb4[(k + 1) * 6 + cg];
        const f32x4 w2v = shb4[(k + 2) * 6 + cg];
        const f32x4 w3v = shb4[(k + 3) * 6 + cg];
        p += a.x * w0 + a.y * w1v + a.z * w2v + a.w * w3v;
    }
    #pragma unroll
    for (int e = 0; e < 4; ++e) {
        const int q = h * NTGT + cg * 4 + e;
        if (r < 512) wABt[(size_t)q * FEAT + r] = f2bf(p[e]);
        else         biasAB[q] = p[e] + t1[((size_t)h * 513 + 512) * 32 + cg * 4 + e];
    }
}

// ---------------------------------------------------------------------------
// gemm1f v3: BM=128 BN=32 BK=64, 32x32x16 MFMA, 3-buffer 2-deep prefetch with
// counted vmcnt(5) (never drains to 0 in the loop), raw s_barrier per iter.
// Staging via global_load_lds (linear LDS dest, inverse-swizzled source).
__global__ __launch_bounds__(256)
void gemm1f(const unsigned short* __restrict__ srcb, const unsigned short* __restrict__ w1t,
            const float* __restrict__ b1, const unsigned short* __restrict__ wABt,
            float* __restrict__ P) {
    __shared__ __align__(16) unsigned short As[3][128 * 64];  // 48 KB
    __shared__ __align__(16) unsigned short Bs[3][32 * 64];   // 12 KB

    const int bid = blockIdx.x;
    const int xcd = bid & 7;
    const int k8  = bid >> 3;               // 0..63
    const int xb  = k8 & 15;                // n-panel 0..15
    const int yb  = (xcd << 2) | (k8 >> 4); // m-panel 0..31
    const int m0 = yb * 128;
    const int n0 = xb * 32;

    const int tid  = threadIdx.x;
    const int lane = tid & 63;
    const int wid  = tid >> 6;              // wave owns rows [wid*32, +32)

    const int aRow = tid >> 3, aCd = (tid & 7) ^ (aRow & 7);
    const int bN   = tid >> 3, bCd = (tid & 7) ^ (bN & 7);
    const size_t aOff = (size_t)(m0 + aRow) * VIS + (aCd << 3);
    const size_t bOff = (size_t)(n0 + bN) * VIS + (bCd << 3);
    const int ldsWb = (wid * 64) << 3;      // wave-uniform slot base (ushorts)

    f32x16 acc = {};

    #define STAGE(tt, bi)                                                        \
        do {                                                                     \
            const int kn_ = (tt) * 64;                                           \
            _Pragma("unroll")                                                    \
            for (int q_ = 0; q_ < 4; ++q_)                                       \
                gload16(srcb + aOff + (size_t)q_ * 32 * VIS + kn_,               \
                        &As[bi][(q_ * 256) * 8 + ldsWb]);                        \
            gload16(w1t + bOff + kn_, &Bs[bi][ldsWb]);                           \
        } while (0)

    STAGE(0, 0);
    STAGE(1, 1);

    const int NT = VIS / 64;                // 32
    for (int t = 0; t < NT; ++t) {
        if (t < NT - 1) asm volatile("s_waitcnt vmcnt(5)" ::: "memory");
        else            asm volatile("s_waitcnt vmcnt(0)" ::: "memory");
        __builtin_amdgcn_s_barrier();
        asm volatile("" ::: "memory");
        if (t + 2 < NT) STAGE(t + 2, (t + 2) % 3);
        const int cb = t % 3;
        #pragma unroll
        for (int k2 = 0; k2 < 4; ++k2) {    // K=64 in 4 x K16 steps
            const int chunk = (k2 << 1) + (lane >> 5);
            short8 af, bf8;
            {
                const int row = wid * 32 + (lane & 31);
                const int cw  = chunk ^ (row & 7);
                af = *reinterpret_cast<const short8*>(&As[cb][(row << 6) + (cw << 3)]);
            }
            {
                const int n  = lane & 31;
                const int cw = chunk ^ (n & 7);
                bf8 = *reinterpret_cast<const short8*>(&Bs[cb][(n << 6) + (cw << 3)]);
            }
            acc = __builtin_amdgcn_mfma_f32_32x32x16_bf16(af, bf8, acc, 0, 0, 0);
        }
    }
    #undef STAGE

    // ---------------- epilogue: bias+relu+pack -> Ht[128][40] ----------------
    // As[0]'s last reader was compute(t=30); all waves passed barrier(31).
    unsigned short* Ht = &As[0][0];
    {
        const float bias = b1[n0 + (lane & 31)];
        #pragma unroll
        for (int r = 0; r < 16; ++r) {
            const int row = wid * 32 + (r & 3) + ((r >> 2) << 3) + ((lane >> 5) << 2);
            const float v = fmaxf(acc[r] + bias, 0.f);
            Ht[row * 40 + (lane & 31)] = f2bf(v);
        }
    }
    __syncthreads();

    // fused projection: wave handles rows [wid*32,+32): 2 m-frags x 3 q-frags
    short8 bq[3];
    #pragma unroll
    for (int t3 = 0; t3 < 3; ++t3)
        bq[t3] = *reinterpret_cast<const short8*>(
            wABt + (size_t)(t3 * 16 + (lane & 15)) * FEAT + n0 + ((lane >> 4) << 3));

    const f32x4 pz = {0.f, 0.f, 0.f, 0.f};
    #pragma unroll
    for (int fr = 0; fr < 2; ++fr) {
        short8 aep;
        {
            const int m = wid * 32 + fr * 16 + (lane & 15);
            aep = *reinterpret_cast<const short8*>(&Ht[m * 40 + ((lane >> 4) << 3)]);
        }
        #pragma unroll
        for (int t3 = 0; t3 < 3; ++t3) {
            f32x4 pp = __builtin_amdgcn_mfma_f32_16x16x32_bf16(aep, bq[t3], pz, 0, 0, 0);
            const int q  = t3 * 16 + (lane & 15);
            const int mb = m0 + wid * 32 + fr * 16 + ((lane >> 4) << 2);
            #pragma unroll
            for (int r = 0; r < 4; ++r)
                atomicAdd(&P[(size_t)(mb + r) * 64 + q], pp[r]);
        }
    }
}

// ---------------------------------------------------------------------------
__global__ __launch_bounds__(256)
void out_loss_kernel(const float* __restrict__ P, const float* __restrict__ br,
                     const float* __restrict__ biasAB, const int* __restrict__ tgt,
                     float* __restrict__ out, float* __restrict__ out_tgt,
                     float* __restrict__ partials) {
    __shared__ float sm[32][49];
    const int bt  = blockIdx.x;
    const int tid = threadIdx.x;
    for (int idx = tid; idx < 32 * 48; idx += 256) {
        const int row = idx / 48, col = idx - row * 48;
        sm[row][col] = P[(size_t)(bt * 32 + row) * 64 + col];
    }
    __syncthreads();

    const int r  = bt * 256 + tid;
    const int i  = tid >> 4, j = tid & 15;
    const int tg = tgt[r];

    float vals[NTGT];
    float mx = -1e30f, vtg = 0.f;
    #pragma unroll
    for (int t = 0; t < NTGT; ++t) {
        const float cv = br[t] + biasAB[t] + biasAB[24 + t];
        const float v  = sm[i][t] + sm[16 + j][24 + t] + cv;
        vals[t] = v;
        mx = fmaxf(mx, v);
        if (t == tg) vtg = v;
    }
    float se = 0.f;
    #pragma unroll
    for (int t = 0; t < NTGT; ++t) se += expf(vals[t] - mx);
    const float lse = mx + logf(se);

    float4* o4 = reinterpret_cast<float4*>(out + (size_t)r * NTGT);
    #pragma unroll
    for (int q = 0; q < 6; ++q)
        o4[q] = make_float4(vals[q * 4], vals[q * 4 + 1], vals[q * 4 + 2], vals[q * 4 + 3]);
    out_tgt[r] = (float)tg;

    const float wcl = (tg == 0) ? 1.f : 100.f;
    float p1 = wcl * (lse - vtg);
    float p2 = wcl;
    #pragma unroll
    for (int off = 32; off > 0; off >>= 1) {
        p1 += __shfl_down(p1, off);
        p2 += __shfl_down(p2, off);
    }
    __shared__ float s1[4], s2[4];
    const int lane = tid & 63, wv = tid >> 6;
    if (lane == 0) { s1[wv] = p1; s2[wv] = p2; }
    __syncthreads();
    if (tid == 0) {
        partials[bt]       = s1[0] + s1[1] + s1[2] + s1[3];
        partials[128 + bt] = s2[0] + s2[1] + s2[2] + s2[3];
    }
}

__global__ void final_loss(const float* __restrict__ partials, float* __restrict__ loss) {
    const int t = threadIdx.x;                       // 64 threads
    float a = partials[t] + partials[t + 64];
    float b = partials[128 + t] + partials[192 + t];
    #pragma unroll
    for (int off = 32; off > 0; off >>= 1) {
        a += __shfl_down(a, off);
        b += __shfl_down(b, off);
    }
    if (t == 0) loss[0] = a / b;
}

// ---------------------------------------------------------------------------
extern "C" void kernel_launch(void* const* d_in, const int* in_sizes, int n_in,
                              void* d_out, int out_size, void* d_ws, size_t ws_size,
                              hipStream_t stream) {
    const float* src = (const float*)d_in[0];
    const int*   tgt = (const int*)d_in[1];
    const float* w1  = (const float*)d_in[2];
    const float* b1  = (const float*)d_in[3];
    const float* w2  = (const float*)d_in[4];
    const float* b2  = (const float*)d_in[5];
    const float* wf  = (const float*)d_in[6];
    const float* bfv = (const float*)d_in[7];
    const float* wr  = (const float*)d_in[8];
    const float* br  = (const float*)d_in[9];

    float* ws = (float*)d_ws;
    unsigned short* w1t   = (unsigned short*)(ws);             // 512x2048 bf16
    unsigned short* srcb  = (unsigned short*)(ws + 524288);    // 4096x2048 bf16
    float*          t1    = ws + 4718592;                      // 2*513*32 f32
    unsigned short* wABt  = (unsigned short*)(ws + 4751424);   // 48x512 bf16
    float*          biasAB = ws + 4763712;                     // 48 (+pad)
    float*          P     = ws + 4763776;                      // 4096x64 f32
    float*          parts = ws + 5025920;                      // 256 f32

    float* out_logits = (float*)d_out;
    float* out_tgt    = out_logits + (size_t)EROWS * NTGT;
    float* out_lossp  = out_tgt + EROWS;

    prep1<<<3098, 256, 0, stream>>>(w1, w1t, wf, bfv, wr, t1, src, srcb, P);
    prep2<<<26, 256, 0, stream>>>(w2, b2, t1, wABt, biasAB);
    gemm1f<<<512, 256, 0, stream>>>(srcb, w1t, b1, wABt, P);
    out_loss_kernel<<<128, 256, 0, stream>>>(P, br, biasAB, tgt,
                                             out_logits, out_tgt, parts);
    final_loss<<<1, 64, 0, stream>>>(parts, out_lossp);
}

// Round 10
// 152.585 us; speedup vs baseline: 1.0725x; 1.0499x over previous
//
#include <hip/hip_runtime.h>
#include <cstddef>
#include <cstdint>

#define NOBJ   16
#define FEAT   512
#define VIS    2048
#define NTGT   24
#define MROWS  4096
#define EROWS  32768
#define NPAN   16      // n-panels in gemm1f; Ppart inner stride = NPAN*48

typedef __attribute__((ext_vector_type(8))) short short8;
typedef __attribute__((ext_vector_type(4))) float f32x4;
typedef __attribute__((ext_vector_type(16))) float f32x16;

__device__ __forceinline__ unsigned short f2bf(float f) {
    union { float f; unsigned int i; } v; v.f = f;
    const unsigned int x = v.i;
    return (unsigned short)((x + 0x7fffu + ((x >> 16) & 1u)) >> 16);  // RTNE
}

// async 16B global -> LDS (dest: wave-uniform base + lane*16)
__device__ __forceinline__ void gload16(const unsigned short* g, unsigned short* l) {
    __builtin_amdgcn_global_load_lds(
        (const __attribute__((address_space(1))) unsigned int*)(const void*)g,
        (__attribute__((address_space(3))) unsigned int*)(void*)l, 16, 0, 0);
}

// ---------------------------------------------------------------------------
// prep1: [0,1024) wtrans | [1024,1050) wchain1 | [1050,2074) src f32->bf16
__global__ __launch_bounds__(256)
void prep1(const float* __restrict__ w1, unsigned short* __restrict__ w1t,
           const float* __restrict__ wf, const float* __restrict__ bfv,
           const float* __restrict__ wr, float* __restrict__ t1,
           const float* __restrict__ src, unsigned short* __restrict__ srcb) {
    __shared__ float shbuf[FEAT * NTGT];   // 48 KB
    const int b   = blockIdx.x;
    const int tid = threadIdx.x;
    if (b < 1024) {
        float (*tile)[33] = (float(*)[33])shbuf;
        const int k0 = (b & 63) * 32;
        const int n0 = (b >> 6) * 32;
        const int tx = tid & 31, ty = tid >> 5;
        #pragma unroll
        for (int r = 0; r < 32; r += 8)
            tile[ty + r][tx] = w1[(size_t)(k0 + ty + r) * FEAT + n0 + tx];
        __syncthreads();
        #pragma unroll
        for (int r = 0; r < 32; r += 8)
            w1t[(size_t)(n0 + ty + r) * VIS + k0 + tx] = f2bf(tile[tx][ty + r]);
    } else if (b < 1050) {
        // wchain1, c-grouped float4: t1[h][krow][c] = sum_j rowk[j]*wr[h][j][c]
        const int bb = b - 1024;           // 0..25
        const int h  = bb / 13, blk = bb % 13;
        const float* wrh = wr + (size_t)h * FEAT * NTGT;
        for (int idx = tid; idx < FEAT * NTGT; idx += 256)
            shbuf[idx] = wrh[idx];
        __syncthreads();
        if (tid < 252) {
            const int krow = blk * 42 + tid / 6;
            const int cg   = tid % 6;
            if (krow <= 512) {
                const float* rowp = (krow < 512) ? (wf + (size_t)krow * FEAT) : bfv;
                const f32x4* shb4 = (const f32x4*)shbuf;
                f32x4 p = {0.f, 0.f, 0.f, 0.f};
                #pragma unroll 4
                for (int j = 0; j < FEAT; j += 4) {
                    const float4 a = *reinterpret_cast<const float4*>(rowp + j);
                    const f32x4 w0 = shb4[(j + 0) * 6 + cg];
                    const f32x4 w1v = shb4[(j + 1) * 6 + cg];
                    const f32x4 w2v = shb4[(j + 2) * 6 + cg];
                    const f32x4 w3v = shb4[(j + 3) * 6 + cg];
                    p += a.x * w0 + a.y * w1v + a.z * w2v + a.w * w3v;
                }
                *reinterpret_cast<f32x4*>(t1 + ((size_t)h * 513 + krow) * 32 + cg * 4) = p;
            }
        }
    } else {
        const int bb = b - 1050;           // src convert: 1024 x 8192 elems
        #pragma unroll
        for (int q = 0; q < 4; ++q) {
            const size_t i = (size_t)bb * 8192 + q * 2048 + tid * 8;
            const float4 a = *reinterpret_cast<const float4*>(src + i);
            const float4 c = *reinterpret_cast<const float4*>(src + i + 4);
            short8 o;
            o[0] = (short)f2bf(a.x); o[1] = (short)f2bf(a.y);
            o[2] = (short)f2bf(a.z); o[3] = (short)f2bf(a.w);
            o[4] = (short)f2bf(c.x); o[5] = (short)f2bf(c.y);
            o[6] = (short)f2bf(c.z); o[7] = (short)f2bf(c.w);
            *reinterpret_cast<short8*>(srcb + i) = o;
        }
    }
}

// ---------------------------------------------------------------------------
// prep2: wchain2, c-grouped float4 (26 blocks).
// wABt[q=h*24+c][r] = bf16(sum_k w2[r][k]*t1[h][k][c]); r==512 -> biasAB
__global__ __launch_bounds__(256)
void prep2(const float* __restrict__ w2, const float* __restrict__ b2,
           const float* __restrict__ t1, unsigned short* __restrict__ wABt,
           float* __restrict__ biasAB) {
    __shared__ float shbuf[FEAT * NTGT];   // 48 KB, packed [k][c] 24 cols
    const int b   = blockIdx.x;            // 0..25
    const int tid = threadIdx.x;
    const int h   = b / 13, blk = b % 13;
    for (int idx = tid; idx < FEAT * NTGT; idx += 256) {
        const int row = idx / NTGT, col = idx - row * NTGT;
        shbuf[idx] = t1[((size_t)h * 513 + row) * 32 + col];
    }
    __syncthreads();
    if (tid >= 252) return;
    const int r  = blk * 42 + tid / 6;
    const int cg = tid % 6;
    if (r > 512) return;
    const float* rowp = (r < 512) ? (w2 + (size_t)r * FEAT) : b2;
    const f32x4* shb4 = (const f32x4*)shbuf;
    f32x4 p = {0.f, 0.f, 0.f, 0.f};
    #pragma unroll 4
    for (int k = 0; k < FEAT; k += 4) {
        const float4 a = *reinterpret_cast<const float4*>(rowp + k);
        const f32x4 w0 = shb4[(k + 0) * 6 + cg];
        const f32x4 w1v = shb4[(k + 1) * 6 + cg];
        const f32x4 w2v = shb4[(k + 2) * 6 + cg];
        const f32x4 w3v = shb4[(k + 3) * 6 + cg];
        p += a.x * w0 + a.y * w1v + a.z * w2v + a.w * w3v;
    }
    #pragma unroll
    for (int e = 0; e < 4; ++e) {
        const int q = h * NTGT + cg * 4 + e;
        if (r < 512) wABt[(size_t)q * FEAT + r] = f2bf(p[e]);
        else         biasAB[q] = p[e] + t1[((size_t)h * 513 + 512) * 32 + cg * 4 + e];
    }
}

// ---------------------------------------------------------------------------
// gemm1f v5: BM=128 BN=32 BK=64, 32x32x16 MFMA. 3-buffer 2-deep prefetch,
// wait-then-barrier invariant (R8-verified): {vmcnt(5); s_barrier; STAGE(t+2);
// compute(t)} — every wave certifies its tile-t loads BEFORE the barrier, so
// cross-wave LDS slices are landed when any wave computes. acc split in 2
// chains. Epilogue: contention-free partial stores Ppart (no atomics).
__global__ __launch_bounds__(256)
void gemm1f(const unsigned short* __restrict__ srcb, const unsigned short* __restrict__ w1t,
            const float* __restrict__ b1, const unsigned short* __restrict__ wABt,
            float* __restrict__ Ppart) {
    __shared__ __align__(16) unsigned short As[3][128 * 64];  // 48 KB
    __shared__ __align__(16) unsigned short Bs[3][32 * 64];   // 12 KB

    const int bid = blockIdx.x;
    const int xcd = bid & 7;
    const int k8  = bid >> 3;               // 0..63
    const int xb  = k8 & 15;                // n-panel 0..15
    const int yb  = (xcd << 2) | (k8 >> 4); // m-panel 0..31
    const int m0 = yb * 128;
    const int n0 = xb * 32;

    const int tid  = threadIdx.x;
    const int lane = tid & 63;
    const int wid  = tid >> 6;              // wave owns rows [wid*32, +32)

    const int aRow = tid >> 3, aCd = (tid & 7) ^ (aRow & 7);
    const int bN   = tid >> 3, bCd = (tid & 7) ^ (bN & 7);
    const size_t aOff = (size_t)(m0 + aRow) * VIS + (aCd << 3);
    const size_t bOff = (size_t)(n0 + bN) * VIS + (bCd << 3);
    const int ldsWb = (wid * 64) << 3;      // wave-uniform slot base (ushorts)

    f32x16 acc0 = {}, acc1 = {};

    #define STAGE(tt, bi)                                                        \
        do {                                                                     \
            const int kn_ = (tt) * 64;                                           \
            _Pragma("unroll")                                                    \
            for (int q_ = 0; q_ < 4; ++q_)                                       \
                gload16(srcb + aOff + (size_t)q_ * 32 * VIS + kn_,               \
                        &As[bi][(q_ * 256) * 8 + ldsWb]);                        \
            gload16(w1t + bOff + kn_, &Bs[bi][ldsWb]);                           \
        } while (0)

    STAGE(0, 0);
    STAGE(1, 1);

    const int NT = VIS / 64;                // 32
    for (int t = 0; t < NT; ++t) {
        if (t < NT - 1) asm volatile("s_waitcnt vmcnt(5)" ::: "memory");
        else            asm volatile("s_waitcnt vmcnt(0)" ::: "memory");
        __builtin_amdgcn_s_barrier();
        asm volatile("" ::: "memory");
        if (t + 2 < NT) STAGE(t + 2, (t + 2) % 3);
        const int cb = t % 3;
        #pragma unroll
        for (int k2 = 0; k2 < 4; ++k2) {    // K=64 in 4 x K16 steps
            const int chunk = (k2 << 1) + (lane >> 5);
            short8 af, bf8;
            {
                const int row = wid * 32 + (lane & 31);
                const int cw  = chunk ^ (row & 7);
                af = *reinterpret_cast<const short8*>(&As[cb][(row << 6) + (cw << 3)]);
            }
            {
                const int n  = lane & 31;
                const int cw = chunk ^ (n & 7);
                bf8 = *reinterpret_cast<const short8*>(&Bs[cb][(n << 6) + (cw << 3)]);
            }
            if (k2 < 2) acc0 = __builtin_amdgcn_mfma_f32_32x32x16_bf16(af, bf8, acc0, 0, 0, 0);
            else        acc1 = __builtin_amdgcn_mfma_f32_32x32x16_bf16(af, bf8, acc1, 0, 0, 0);
        }
    }
    #undef STAGE
    acc0 += acc1;

    // ---------------- epilogue: bias+relu+pack -> Ht[128][40] ----------------
    // As[0]'s last reader was compute(t=30); all waves passed barrier(t=31).
    unsigned short* Ht = &As[0][0];
    {
        const float bias = b1[n0 + (lane & 31)];
        #pragma unroll
        for (int r = 0; r < 16; ++r) {
            const int row = wid * 32 + (r & 3) + ((r >> 2) << 3) + ((lane >> 5) << 2);
            const float v = fmaxf(acc0[r] + bias, 0.f);
            Ht[row * 40 + (lane & 31)] = f2bf(v);
        }
    }
    __syncthreads();

    // fused projection: wave handles rows [wid*32,+32): 2 m-frags x 3 q-frags
    short8 bq[3];
    #pragma unroll
    for (int t3 = 0; t3 < 3; ++t3)
        bq[t3] = *reinterpret_cast<const short8*>(
            wABt + (size_t)(t3 * 16 + (lane & 15)) * FEAT + n0 + ((lane >> 4) << 3));

    const f32x4 pz = {0.f, 0.f, 0.f, 0.f};
    #pragma unroll
    for (int fr = 0; fr < 2; ++fr) {
        short8 aep;
        {
            const int m = wid * 32 + fr * 16 + (lane & 15);
            aep = *reinterpret_cast<const short8*>(&Ht[m * 40 + ((lane >> 4) << 3)]);
        }
        #pragma unroll
        for (int t3 = 0; t3 < 3; ++t3) {
            f32x4 pp = __builtin_amdgcn_mfma_f32_16x16x32_bf16(aep, bq[t3], pz, 0, 0, 0);
            const int q  = t3 * 16 + (lane & 15);
            const int mb = m0 + wid * 32 + fr * 16 + ((lane >> 4) << 2);
            #pragma unroll
            for (int r = 0; r < 4; ++r)
                Ppart[(size_t)(mb + r) * (NPAN * 48) + xb * 48 + q] = pp[r];
        }
    }
}

// ---------------------------------------------------------------------------
// out_loss: one block per bt. Sums the 16 n-panel partials of Ppart while
// staging into LDS, then assembles logits + weighted-CE partials.
__global__ __launch_bounds__(256)
void out_loss_kernel(const float* __restrict__ Ppart, const float* __restrict__ br,
                     const float* __restrict__ biasAB, const int* __restrict__ tgt,
                     float* __restrict__ out, float* __restrict__ out_tgt,
                     float* __restrict__ partials) {
    __shared__ float sm[32][49];
    const int bt  = blockIdx.x;
    const int tid = threadIdx.x;
    const float* Pp = Ppart + (size_t)bt * 32 * (NPAN * 48);
    for (int idx = tid; idx < 32 * 48; idx += 256) {
        const int row = idx / 48, col = idx - row * 48;
        const float* rp = Pp + (size_t)row * (NPAN * 48) + col;
        float s = 0.f;
        #pragma unroll
        for (int p = 0; p < NPAN; ++p) s += rp[p * 48];
        sm[row][col] = s;
    }
    __syncthreads();

    const int r  = bt * 256 + tid;
    const int i  = tid >> 4, j = tid & 15;
    const int tg = tgt[r];

    float vals[NTGT];
    float mx = -1e30f, vtg = 0.f;
    #pragma unroll
    for (int t = 0; t < NTGT; ++t) {
        const float cv = br[t] + biasAB[t] + biasAB[24 + t];
        const float v  = sm[i][t] + sm[16 + j][24 + t] + cv;
        vals[t] = v;
        mx = fmaxf(mx, v);
        if (t == tg) vtg = v;
    }
    float se = 0.f;
    #pragma unroll
    for (int t = 0; t < NTGT; ++t) se += expf(vals[t] - mx);
    const float lse = mx + logf(se);

    float4* o4 = reinterpret_cast<float4*>(out + (size_t)r * NTGT);
    #pragma unroll
    for (int q = 0; q < 6; ++q)
        o4[q] = make_float4(vals[q * 4], vals[q * 4 + 1], vals[q * 4 + 2], vals[q * 4 + 3]);
    out_tgt[r] = (float)tg;

    const float wcl = (tg == 0) ? 1.f : 100.f;
    float p1 = wcl * (lse - vtg);
    float p2 = wcl;
    #pragma unroll
    for (int off = 32; off > 0; off >>= 1) {
        p1 += __shfl_down(p1, off);
        p2 += __shfl_down(p2, off);
    }
    __shared__ float s1[4], s2[4];
    const int lane = tid & 63, wv = tid >> 6;
    if (lane == 0) { s1[wv] = p1; s2[wv] = p2; }
    __syncthreads();
    if (tid == 0) {
        partials[bt]       = s1[0] + s1[1] + s1[2] + s1[3];
        partials[128 + bt] = s2[0] + s2[1] + s2[2] + s2[3];
    }
}

__global__ void final_loss(const float* __restrict__ partials, float* __restrict__ loss) {
    const int t = threadIdx.x;                       // 64 threads
    float a = partials[t] + partials[t + 64];
    float b = partials[128 + t] + partials[192 + t];
    #pragma unroll
    for (int off = 32; off > 0; off >>= 1) {
        a += __shfl_down(a, off);
        b += __shfl_down(b, off);
    }
    if (t == 0) loss[0] = a / b;
}

// ---------------------------------------------------------------------------
extern "C" void kernel_launch(void* const* d_in, const int* in_sizes, int n_in,
                              void* d_out, int out_size, void* d_ws, size_t ws_size,
                              hipStream_t stream) {
    const float* src = (const float*)d_in[0];
    const int*   tgt = (const int*)d_in[1];
    const float* w1  = (const float*)d_in[2];
    const float* b1  = (const float*)d_in[3];
    const float* w2  = (const float*)d_in[4];
    const float* b2  = (const float*)d_in[5];
    const float* wf  = (const float*)d_in[6];
    const float* bfv = (const float*)d_in[7];
    const float* wr  = (const float*)d_in[8];
    const float* br  = (const float*)d_in[9];

    float* ws = (float*)d_ws;
    unsigned short* w1t   = (unsigned short*)(ws);             // 512x2048 bf16
    unsigned short* srcb  = (unsigned short*)(ws + 524288);    // 4096x2048 bf16
    float*          t1    = ws + 4718592;                      // 2*513*32 f32
    unsigned short* wABt  = (unsigned short*)(ws + 4751424);   // 48x512 bf16
    float*          biasAB = ws + 4763712;                     // 48 (+pad)
    float*          Ppart = ws + 4763776;                      // 4096x16x48 f32
    float*          parts = ws + 7909504;                      // 256 f32

    float* out_logits = (float*)d_out;
    float* out_tgt    = out_logits + (size_t)EROWS * NTGT;
    float* out_lossp  = out_tgt + EROWS;

    prep1<<<2074, 256, 0, stream>>>(w1, w1t, wf, bfv, wr, t1, src, srcb);
    prep2<<<26, 256, 0, stream>>>(w2, b2, t1, wABt, biasAB);
    gemm1f<<<512, 256, 0, stream>>>(srcb, w1t, b1, wABt, Ppart);
    out_loss_kernel<<<128, 256, 0, stream>>>(Ppart, br, biasAB, tgt,
                                             out_logits, out_tgt, parts);
    final_loss<<<1, 64, 0, stream>>>(parts, out_lossp);
}